// Round 1
// baseline (276.277 us; speedup 1.0000x reference)
//
#include <hip/hip_runtime.h>
#include <stdint.h>

typedef _Float16 half8  __attribute__((ext_vector_type(8)));
typedef _Float16 half4v __attribute__((ext_vector_type(4)));
typedef float    floatx4 __attribute__((ext_vector_type(4)));

#define LOG2E 1.44269504088896340736f

// async global->LDS 16B copy (LDS dest must be wave-uniform base + lane*16)
__device__ __forceinline__ void gl_lds16(const _Float16* g, _Float16* l) {
  __builtin_amdgcn_global_load_lds(
      (__attribute__((address_space(1))) void*)g,
      (__attribute__((address_space(3))) void*)l, 16, 0, 0);
}

// exp2 via v_exp_f32; s_nop covers the trans-op wait-state hazard
__device__ __forceinline__ float exp2_fast(float x) {
  float r;
  asm volatile("v_exp_f32 %0, %1\n\ts_nop 1" : "=v"(r) : "v"(x));
  return r;
}

// ---------------- kernel 1: fp32 -> f16 convert ----------------
struct CvtArgs {
  const float* src[6];
  _Float16*    dst[6];
  int          n[6];
};

__global__ void cvt_kernel(CvtArgs a) {
  const int z = blockIdx.y;
  const int n = a.n[z];
  const int i = (blockIdx.x * 256 + threadIdx.x) * 8;
  if (i >= n) return;
  const float4* s = (const float4*)(a.src[z] + i);
  float4 v0 = s[0], v1 = s[1];
  half8 h = { (_Float16)v0.x, (_Float16)v0.y, (_Float16)v0.z, (_Float16)v0.w,
              (_Float16)v1.x, (_Float16)v1.y, (_Float16)v1.z, (_Float16)v1.w };
  *(half8*)(a.dst[z] + i) = h;
}

// ---------------- kernel 2: QKV projection GEMM -----------------
// C[m,n] = X[m,:] . W[n,:] + b[n]   (torch Linear, both K-contiguous)
// z=0: Q -> [48][2048][64] * log2e ; z=1: K -> [48][2048][64] ; z=2: V -> [48][64][2048] (transposed)
__global__ __launch_bounds__(256, 2) void qkv_gemm(
    const _Float16* __restrict__ xh, const _Float16* __restrict__ wh,
    const float* __restrict__ bqp, const float* __restrict__ bkp, const float* __restrict__ bvp,
    _Float16* __restrict__ oq, _Float16* __restrict__ ok, _Float16* __restrict__ ovt)
{
  __shared__ __attribute__((aligned(16))) _Float16 As[128 * 32];
  __shared__ __attribute__((aligned(16))) _Float16 Bs[128 * 32];
  const int z  = blockIdx.z;
  const _Float16* X = xh + (size_t)z * 8192 * 768;
  const _Float16* W = wh + (size_t)z * 768 * 768;
  const int m0 = blockIdx.x * 128, n0 = blockIdx.y * 128;
  const int tid  = threadIdx.x;
  const int lane = tid & 63, wid = tid >> 6;
  const int wr = wid >> 1, wc = wid & 1;
  const int qd = lane >> 4, col = lane & 15;

  const floatx4 z4 = {0.f, 0.f, 0.f, 0.f};
  floatx4 acc[4][4];
  #pragma unroll
  for (int i = 0; i < 4; ++i)
    #pragma unroll
    for (int j = 0; j < 4; ++j) acc[i][j] = z4;

  const int c0 = tid, c1 = 256 + tid;
  const int ar0 = c0 >> 2, ac0 = (c0 & 3) * 8;
  const int ar1 = c1 >> 2, ac1 = (c1 & 3) * 8;

  for (int k0 = 0; k0 < 768; k0 += 32) {
    __syncthreads();
    gl_lds16(X + (size_t)(m0 + ar0) * 768 + k0 + ac0, As + c0 * 8);
    gl_lds16(X + (size_t)(m0 + ar1) * 768 + k0 + ac1, As + c1 * 8);
    gl_lds16(W + (size_t)(n0 + ar0) * 768 + k0 + ac0, Bs + c0 * 8);
    gl_lds16(W + (size_t)(n0 + ar1) * 768 + k0 + ac1, Bs + c1 * 8);
    __syncthreads();
    half8 af[4], bf[4];
    #pragma unroll
    for (int t = 0; t < 4; ++t)
      af[t] = *(const half8*)(As + (wr * 64 + t * 16 + col) * 32 + qd * 8);
    #pragma unroll
    for (int t = 0; t < 4; ++t)
      bf[t] = *(const half8*)(Bs + (wc * 64 + t * 16 + col) * 32 + qd * 8);
    #pragma unroll
    for (int i = 0; i < 4; ++i)
      #pragma unroll
      for (int j = 0; j < 4; ++j)
        acc[i][j] = __builtin_amdgcn_mfma_f32_16x16x32_f16(af[i], bf[j], acc[i][j], 0, 0, 0);
  }

  const float* bias = (z == 0) ? bqp : ((z == 1) ? bkp : bvp);
  if (z == 2) {
    // V transposed: vt[(b*768 + n)*2048 + s]; lane's 4 regs = 4 consecutive seq rows -> 8B store
    #pragma unroll
    for (int j = 0; j < 4; ++j) {
      int n = n0 + wc * 64 + j * 16 + col;
      float bb = bias[n];
      #pragma unroll
      for (int i = 0; i < 4; ++i) {
        int m = m0 + wr * 64 + i * 16 + qd * 4;
        int b = m >> 11, s = m & 2047;
        half4v h;
        #pragma unroll
        for (int r = 0; r < 4; ++r) h[r] = (_Float16)(acc[i][j][r] + bb);
        *(half4v*)(ovt + ((size_t)(b * 768 + n)) * 2048 + s) = h;
      }
    }
  } else {
    _Float16* O = (z == 0) ? oq : ok;
    const float scale = (z == 0) ? LOG2E : 1.0f;   // fold log2e into Q for exp2-domain softmax
    #pragma unroll
    for (int j = 0; j < 4; ++j) {
      int n = n0 + wc * 64 + j * 16 + col;
      float bb = bias[n];
      int hh = n >> 6, d = n & 63;
      #pragma unroll
      for (int i = 0; i < 4; ++i) {
        int m = m0 + wr * 64 + i * 16 + qd * 4;
        int b = m >> 11, s = m & 2047;
        _Float16* p = O + (size_t)(b * 12 + hh) * 131072 + (size_t)s * 64 + d;
        #pragma unroll
        for (int r = 0; r < 4; ++r) p[(size_t)r * 64] = (_Float16)((acc[i][j][r] + bb) * scale);
      }
    }
  }
}

// ---------------- kernel 3: flash attention -----------------
// Computes S^T = K.Q^T per tile (C-layout: row=key, col=q), online softmax in exp2 domain
// (Q pre-scaled by log2e), PV as out^T = V^T . P with P transposed via per-wave LDS chunks.
__global__ __launch_bounds__(256, 2) void attn_kernel(
    const _Float16* __restrict__ Qm,   // [48][2048][64] (log2e-scaled)
    const _Float16* __restrict__ Km,   // [48][2048][64]
    const _Float16* __restrict__ Vt,   // [48][64][2048]
    float* __restrict__ out)           // [4][2048][768]
{
  __shared__ __attribute__((aligned(16))) _Float16 Qs[128 * 64];
  __shared__ __attribute__((aligned(16))) _Float16 Ks[128 * 64];
  __shared__ __attribute__((aligned(16))) _Float16 Vs[64 * 128];
  const int bh = blockIdx.y;
  const int q0 = blockIdx.x * 128;
  const int tid = threadIdx.x, lane = tid & 63, w = tid >> 6;
  const int qd = lane >> 4, col = lane & 15;
  const _Float16* Qg = Qm + (size_t)bh * 131072;
  const _Float16* Kg = Km + (size_t)bh * 131072;
  const _Float16* Vg = Vt + (size_t)bh * 131072;

  // stage Q tile (XOR-swizzled rows: 64-half rows would be 16-way bank conflicts)
  #pragma unroll
  for (int i = 0; i < 4; ++i) {
    int cc = i * 256 + tid, row = cc >> 3, pc = cc & 7;
    gl_lds16(Qg + (size_t)(q0 + row) * 64 + ((pc ^ (row & 7)) * 8), Qs + cc * 8);
  }
  __syncthreads();
  half8 qf[2][2];   // B-operand frags, kept in registers for all K-tiles
  #pragma unroll
  for (int qt = 0; qt < 2; ++qt)
    #pragma unroll
    for (int ks = 0; ks < 2; ++ks) {
      int row = w * 32 + qt * 16 + col;
      qf[qt][ks] = *(const half8*)(Qs + row * 64 + (((ks * 4 + qd) ^ (row & 7)) * 8));
    }
  // Q LDS quarter becomes this wave's private P scratch: [32 q][40 halfs] per 32-key chunk
  _Float16* Pb = Qs + w * 2048;

  float m2[2]   = {-INFINITY, -INFINITY};
  float lsum[2] = {0.f, 0.f};
  const floatx4 z4 = {0.f, 0.f, 0.f, 0.f};
  floatx4 o[4][2];
  #pragma unroll
  for (int dt = 0; dt < 4; ++dt)
    #pragma unroll
    for (int qt = 0; qt < 2; ++qt) o[dt][qt] = z4;

  for (int j0 = 0; j0 < 2048; j0 += 128) {
    __syncthreads();
    #pragma unroll
    for (int i = 0; i < 4; ++i) {
      int cc = i * 256 + tid, row = cc >> 3, pc = cc & 7;
      gl_lds16(Kg + (size_t)(j0 + row) * 64 + ((pc ^ (row & 7)) * 8), Ks + cc * 8);
    }
    #pragma unroll
    for (int i = 0; i < 4; ++i) {
      int cc = i * 256 + tid, row = cc >> 4, pc = cc & 15;
      gl_lds16(Vg + (size_t)row * 2048 + j0 + ((pc ^ (row & 15)) * 8), Vs + cc * 8);
    }
    __syncthreads();

    // S^T = K . Q^T : 8 key-tiles x 2 q-tiles, contraction d=64 (2 steps)
    floatx4 st[8][2];
    #pragma unroll
    for (int t = 0; t < 8; ++t)
      #pragma unroll
      for (int qt = 0; qt < 2; ++qt) st[t][qt] = z4;
    #pragma unroll
    for (int t = 0; t < 8; ++t) {
      int row = t * 16 + col;
      #pragma unroll
      for (int ks = 0; ks < 2; ++ks) {
        half8 kf = *(const half8*)(Ks + row * 64 + (((ks * 4 + qd) ^ (row & 7)) * 8));
        #pragma unroll
        for (int qt = 0; qt < 2; ++qt)
          st[t][qt] = __builtin_amdgcn_mfma_f32_16x16x32_f16(kf, qf[qt][ks], st[t][qt], 0, 0, 0);
      }
    }

    // online softmax over keys (= quad/reg axis): in-lane tree + 2 shuffles
    #pragma unroll
    for (int qt = 0; qt < 2; ++qt) {
      float mx = -INFINITY;
      #pragma unroll
      for (int t = 0; t < 8; ++t) {
        floatx4 s = st[t][qt];
        mx = fmaxf(mx, fmaxf(fmaxf(s[0], s[1]), fmaxf(s[2], s[3])));
      }
      mx = fmaxf(mx, __shfl_xor(mx, 16, 64));
      mx = fmaxf(mx, __shfl_xor(mx, 32, 64));
      float mo = m2[qt];
      float mn = fmaxf(mo, mx);
      m2[qt] = mn;
      float alpha = exp2_fast(mo - mn);
      float rs = 0.f;
      #pragma unroll
      for (int t = 0; t < 8; ++t) {
        floatx4 s = st[t][qt];
        s[0] = exp2_fast(s[0] - mn);
        s[1] = exp2_fast(s[1] - mn);
        s[2] = exp2_fast(s[2] - mn);
        s[3] = exp2_fast(s[3] - mn);
        rs += (s[0] + s[1]) + (s[2] + s[3]);
        st[t][qt] = s;
      }
      rs += __shfl_xor(rs, 16, 64);
      rs += __shfl_xor(rs, 32, 64);
      lsum[qt] = lsum[qt] * alpha + rs;
      #pragma unroll
      for (int dt = 0; dt < 4; ++dt) {
        o[dt][qt][0] *= alpha; o[dt][qt][1] *= alpha;
        o[dt][qt][2] *= alpha; o[dt][qt][3] *= alpha;
      }
    }

    // PV in 32-key chunks: lane's 4 regs = 4 consecutive keys -> one ds_write_b64 per tile
    #pragma unroll
    for (int c = 0; c < 4; ++c) {
      #pragma unroll
      for (int tt = 0; tt < 2; ++tt) {
        int t = 2 * c + tt;
        #pragma unroll
        for (int qt = 0; qt < 2; ++qt) {
          int qq = qt * 16 + col;
          floatx4 s = st[t][qt];
          half4v p4 = {(_Float16)s[0], (_Float16)s[1], (_Float16)s[2], (_Float16)s[3]};
          *(half4v*)(Pb + qq * 40 + tt * 16 + qd * 4) = p4;
        }
      }
      half8 vf[4];
      #pragma unroll
      for (int dt = 0; dt < 4; ++dt) {
        int row = dt * 16 + col;
        vf[dt] = *(const half8*)(Vs + row * 128 + (((c * 4 + qd) ^ (row & 15)) * 8));
      }
      #pragma unroll
      for (int qt = 0; qt < 2; ++qt) {
        int qq = qt * 16 + col;
        half8 pf = *(const half8*)(Pb + qq * 40 + qd * 8);
        #pragma unroll
        for (int dt = 0; dt < 4; ++dt)
          o[dt][qt] = __builtin_amdgcn_mfma_f32_16x16x32_f16(vf[dt], pf, o[dt][qt], 0, 0, 0);
      }
    }
  }

  // epilogue: out^T C-layout -> lane holds 4 consecutive d for fixed q -> float4 stores
  const int b = bh / 12, h = bh % 12;
  #pragma unroll
  for (int qt = 0; qt < 2; ++qt) {
    float inv = 1.0f / lsum[qt];
    int qg = q0 + w * 32 + qt * 16 + col;
    float* obase = out + ((size_t)b * 2048 + qg) * 768 + h * 64;
    #pragma unroll
    for (int dt = 0; dt < 4; ++dt) {
      floatx4 v = o[dt][qt];
      v[0] *= inv; v[1] *= inv; v[2] *= inv; v[3] *= inv;
      *(floatx4*)(obase + dt * 16 + qd * 4) = v;
    }
  }
}

// ---------------- launcher ----------------
extern "C" void kernel_launch(void* const* d_in, const int* in_sizes, int n_in,
                              void* d_out, int out_size, void* d_ws, size_t ws_size,
                              hipStream_t stream) {
  const float* q  = (const float*)d_in[0];
  const float* k  = (const float*)d_in[1];
  const float* v  = (const float*)d_in[2];
  const float* Wq = (const float*)d_in[3];
  const float* bq = (const float*)d_in[4];
  const float* Wk = (const float*)d_in[5];
  const float* bk = (const float*)d_in[6];
  const float* Wv = (const float*)d_in[7];
  const float* bv = (const float*)d_in[8];

  const size_t NX = 6291456;   // 4*2048*768
  const size_t NW = 589824;    // 768*768
  const size_t need = (3 * NX + 3 * NW + 3 * NX) * sizeof(_Float16);
  if (ws_size < need) return;

  _Float16* xh = (_Float16*)d_ws;            // [3][8192][768] f16 inputs
  _Float16* wh = xh + 3 * NX;                // [3][768][768] f16 weights
  _Float16* qh = wh + 3 * NW;                // Q' [48][2048][64] (log2e-scaled)
  _Float16* kh = qh + NX;                    // K' [48][2048][64]
  _Float16* vt = kh + NX;                    // V'^T [48][64][2048]

  CvtArgs ca;
  ca.src[0] = q;  ca.src[1] = k;  ca.src[2] = v;
  ca.src[3] = Wq; ca.src[4] = Wk; ca.src[5] = Wv;
  ca.dst[0] = xh;          ca.dst[1] = xh + NX;     ca.dst[2] = xh + 2 * NX;
  ca.dst[3] = wh;          ca.dst[4] = wh + NW;     ca.dst[5] = wh + 2 * NW;
  ca.n[0] = (int)NX; ca.n[1] = (int)NX; ca.n[2] = (int)NX;
  ca.n[3] = (int)NW; ca.n[4] = (int)NW; ca.n[5] = (int)NW;

  cvt_kernel<<<dim3(3072, 6), 256, 0, stream>>>(ca);
  qkv_gemm<<<dim3(64, 6, 3), 256, 0, stream>>>(xh, wh, bq, bk, bv, qh, kh, vt);
  attn_kernel<<<dim3(16, 48), 256, 0, stream>>>(qh, kh, vt, (float*)d_out);
}

// Round 3
// 255.711 us; speedup vs baseline: 1.0804x; 1.0804x over previous
//
#include <hip/hip_runtime.h>
#include <stdint.h>

typedef _Float16 half8  __attribute__((ext_vector_type(8)));
typedef _Float16 half4v __attribute__((ext_vector_type(4)));
typedef float    floatx4 __attribute__((ext_vector_type(4)));

#define LOG2E 1.44269504088896340736f

// async global->LDS 16B copy (LDS dest must be wave-uniform base + lane*16)
__device__ __forceinline__ void gl_lds16(const _Float16* g, _Float16* l) {
  __builtin_amdgcn_global_load_lds(
      (__attribute__((address_space(1))) void*)g,
      (__attribute__((address_space(3))) void*)l, 16, 0, 0);
}

// ---------------- kernel 1: fp32 -> f16 convert ----------------
struct CvtArgs {
  const float* src[6];
  _Float16*    dst[6];
  int          n[6];
};

__global__ void cvt_kernel(CvtArgs a) {
  const int z = blockIdx.y;
  const int n = a.n[z];
  const int i = (blockIdx.x * 256 + threadIdx.x) * 8;
  if (i >= n) return;
  const float4* s = (const float4*)(a.src[z] + i);
  float4 v0 = s[0], v1 = s[1];
  half8 h = { (_Float16)v0.x, (_Float16)v0.y, (_Float16)v0.z, (_Float16)v0.w,
              (_Float16)v1.x, (_Float16)v1.y, (_Float16)v1.z, (_Float16)v1.w };
  *(half8*)(a.dst[z] + i) = h;
}

// ---------------- kernel 2: QKV projection GEMM -----------------
// C[m,n] = X[m,:] . W[n,:] + b[n]   (torch Linear, both K-contiguous)
// z=0: Q -> [48][2048][64] * log2e ; z=1: K -> [48][2048][64] ; z=2: V -> [48][64][2048] (transposed)
__global__ __launch_bounds__(256, 2) void qkv_gemm(
    const _Float16* __restrict__ xh, const _Float16* __restrict__ wh,
    const float* __restrict__ bqp, const float* __restrict__ bkp, const float* __restrict__ bvp,
    _Float16* __restrict__ oq, _Float16* __restrict__ ok, _Float16* __restrict__ ovt)
{
  __shared__ __attribute__((aligned(16))) _Float16 As[128 * 32];
  __shared__ __attribute__((aligned(16))) _Float16 Bs[128 * 32];
  const int z  = blockIdx.z;
  const _Float16* X = xh + (size_t)z * 8192 * 768;
  const _Float16* W = wh + (size_t)z * 768 * 768;
  const int m0 = blockIdx.x * 128, n0 = blockIdx.y * 128;
  const int tid  = threadIdx.x;
  const int lane = tid & 63, wid = tid >> 6;
  const int wr = wid >> 1, wc = wid & 1;
  const int qd = lane >> 4, col = lane & 15;

  const floatx4 z4 = {0.f, 0.f, 0.f, 0.f};
  floatx4 acc[4][4];
  #pragma unroll
  for (int i = 0; i < 4; ++i)
    #pragma unroll
    for (int j = 0; j < 4; ++j) acc[i][j] = z4;

  const int c0 = tid, c1 = 256 + tid;
  const int ar0 = c0 >> 2, ac0 = (c0 & 3) * 8;
  const int ar1 = c1 >> 2, ac1 = (c1 & 3) * 8;

  for (int k0 = 0; k0 < 768; k0 += 32) {
    __syncthreads();
    gl_lds16(X + (size_t)(m0 + ar0) * 768 + k0 + ac0, As + c0 * 8);
    gl_lds16(X + (size_t)(m0 + ar1) * 768 + k0 + ac1, As + c1 * 8);
    gl_lds16(W + (size_t)(n0 + ar0) * 768 + k0 + ac0, Bs + c0 * 8);
    gl_lds16(W + (size_t)(n0 + ar1) * 768 + k0 + ac1, Bs + c1 * 8);
    __syncthreads();
    half8 af[4], bf[4];
    #pragma unroll
    for (int t = 0; t < 4; ++t)
      af[t] = *(const half8*)(As + (wr * 64 + t * 16 + col) * 32 + qd * 8);
    #pragma unroll
    for (int t = 0; t < 4; ++t)
      bf[t] = *(const half8*)(Bs + (wc * 64 + t * 16 + col) * 32 + qd * 8);
    #pragma unroll
    for (int i = 0; i < 4; ++i)
      #pragma unroll
      for (int j = 0; j < 4; ++j)
        acc[i][j] = __builtin_amdgcn_mfma_f32_16x16x32_f16(af[i], bf[j], acc[i][j], 0, 0, 0);
  }

  const float* bias = (z == 0) ? bqp : ((z == 1) ? bkp : bvp);
  if (z == 2) {
    // V transposed: vt[(b*768 + n)*2048 + s]; lane's 4 regs = 4 consecutive seq rows -> 8B store
    #pragma unroll
    for (int j = 0; j < 4; ++j) {
      int n = n0 + wc * 64 + j * 16 + col;
      float bb = bias[n];
      #pragma unroll
      for (int i = 0; i < 4; ++i) {
        int m = m0 + wr * 64 + i * 16 + qd * 4;
        int b = m >> 11, s = m & 2047;
        half4v h;
        #pragma unroll
        for (int r = 0; r < 4; ++r) h[r] = (_Float16)(acc[i][j][r] + bb);
        *(half4v*)(ovt + ((size_t)(b * 768 + n)) * 2048 + s) = h;
      }
    }
  } else {
    _Float16* O = (z == 0) ? oq : ok;
    const float scale = (z == 0) ? LOG2E : 1.0f;   // fold log2e into Q for exp2-domain softmax
    #pragma unroll
    for (int j = 0; j < 4; ++j) {
      int n = n0 + wc * 64 + j * 16 + col;
      float bb = bias[n];
      int hh = n >> 6, d = n & 63;
      #pragma unroll
      for (int i = 0; i < 4; ++i) {
        int m = m0 + wr * 64 + i * 16 + qd * 4;
        int b = m >> 11, s = m & 2047;
        _Float16* p = O + (size_t)(b * 12 + hh) * 131072 + (size_t)s * 64 + d;
        #pragma unroll
        for (int r = 0; r < 4; ++r) p[(size_t)r * 64] = (_Float16)((acc[i][j][r] + bb) * scale);
      }
    }
  }
}

// ---------------- kernel 3: flash attention -----------------
// S^T = K.Q^T (C-layout: row=key, col=q). Online softmax in exp2 domain (Q pre-scaled
// by log2e). PV uses 16x16x16 MFMA: its B-operand layout == S^T's C-layout, so P goes
// straight from accumulator regs (2 cvt_pkrtz) into MFMA — no LDS transpose at all.
// K/V 64-key tiles, double-buffered; prefetch issued before compute so the barrier's
// vmcnt(0) drain finds loads already complete. Q frags loaded direct from global.

__device__ __forceinline__ void stage_kv(const _Float16* __restrict__ Kg,
                                         const _Float16* __restrict__ Vg,
                                         _Float16* ksd, _Float16* vsd, int j0, int tid) {
  #pragma unroll
  for (int i = 0; i < 2; ++i) {
    int c = i * 256 + tid;
    int row = c >> 3, sc = c & 7;
    gl_lds16(Kg + (size_t)(j0 + row) * 64 + ((sc ^ (row & 7)) * 8), ksd + c * 8);
    gl_lds16(Vg + (size_t)row * 2048 + j0 + ((sc ^ (row & 7)) * 8), vsd + c * 8);
  }
}

template <int BUF>
__device__ __forceinline__ void attn_body(
    int jnext, const _Float16* __restrict__ Kg, const _Float16* __restrict__ Vg,
    _Float16* Ks, _Float16* Vs, int tid,
    const half8 (&qf)[2][2], int kb0, int kb1, const int (&vb)[4],
    float (&m)[2], float (&l)[2], floatx4 (&o)[4][2])
{
  if (jnext < 2048)
    stage_kv(Kg, Vg, Ks + (1 - BUF) * 4096, Vs + (1 - BUF) * 4096, jnext, tid);

  const char* ksb = (const char*)Ks;
  const char* vsb = (const char*)Vs;
  const floatx4 z4 = {0.f, 0.f, 0.f, 0.f};

  // S^T = K . Q^T : 4 key-tiles x 2 q-tiles, contraction d=64 in 2 steps
  floatx4 st[4][2];
  #pragma unroll
  for (int t = 0; t < 4; ++t) {
    half8 kf0 = *(const half8*)(ksb + BUF * 8192 + t * 2048 + kb0);
    half8 kf1 = *(const half8*)(ksb + BUF * 8192 + t * 2048 + kb1);
    #pragma unroll
    for (int qt = 0; qt < 2; ++qt) {
      st[t][qt] = __builtin_amdgcn_mfma_f32_16x16x32_f16(kf0, qf[qt][0], z4, 0, 0, 0);
      st[t][qt] = __builtin_amdgcn_mfma_f32_16x16x32_f16(kf1, qf[qt][1], st[t][qt], 0, 0, 0);
    }
  }

  // online softmax over keys (quad/reg axis): in-lane tree + 2 shuffles
  float mn[2], rs[2];
  half4v pf[4][2];
  #pragma unroll
  for (int qt = 0; qt < 2; ++qt) {
    float mx = fmaxf(
        fmaxf(fmaxf(fmaxf(st[0][qt][0], st[0][qt][1]), fmaxf(st[0][qt][2], st[0][qt][3])),
              fmaxf(fmaxf(st[1][qt][0], st[1][qt][1]), fmaxf(st[1][qt][2], st[1][qt][3]))),
        fmaxf(fmaxf(fmaxf(st[2][qt][0], st[2][qt][1]), fmaxf(st[2][qt][2], st[2][qt][3])),
              fmaxf(fmaxf(st[3][qt][0], st[3][qt][1]), fmaxf(st[3][qt][2], st[3][qt][3]))));
    mx = fmaxf(mx, __shfl_xor(mx, 16, 64));
    mx = fmaxf(mx, __shfl_xor(mx, 32, 64));
    mn[qt] = fmaxf(m[qt], mx);
  }
  bool upd = (mn[0] > m[0]) || (mn[1] > m[1]);

  #pragma unroll
  for (int qt = 0; qt < 2; ++qt) {
    float r = 0.f;
    #pragma unroll
    for (int t = 0; t < 4; ++t) {
      float e0 = __builtin_amdgcn_exp2f(st[t][qt][0] - mn[qt]);
      float e1 = __builtin_amdgcn_exp2f(st[t][qt][1] - mn[qt]);
      float e2 = __builtin_amdgcn_exp2f(st[t][qt][2] - mn[qt]);
      float e3 = __builtin_amdgcn_exp2f(st[t][qt][3] - mn[qt]);
      auto lo = __builtin_amdgcn_cvt_pkrtz(e0, e1);
      auto hi = __builtin_amdgcn_cvt_pkrtz(e2, e3);
      half4v p = {static_cast<_Float16>(lo[0]), static_cast<_Float16>(lo[1]),
                  static_cast<_Float16>(hi[0]), static_cast<_Float16>(hi[1])};
      pf[t][qt] = p;
      r += (e0 + e1) + (e2 + e3);
    }
    r += __shfl_xor(r, 16, 64);
    r += __shfl_xor(r, 32, 64);
    rs[qt] = r;
  }

  if (__any(upd)) {
    #pragma unroll
    for (int qt = 0; qt < 2; ++qt) {
      float alpha = __builtin_amdgcn_exp2f(m[qt] - mn[qt]);
      m[qt] = mn[qt];
      l[qt] = l[qt] * alpha + rs[qt];
      #pragma unroll
      for (int dt = 0; dt < 4; ++dt) {
        o[dt][qt][0] *= alpha; o[dt][qt][1] *= alpha;
        o[dt][qt][2] *= alpha; o[dt][qt][3] *= alpha;
      }
    }
  } else {
    l[0] += rs[0];
    l[1] += rs[1];
  }

  // PV: out^T = V^T . P, contraction 16 keys per MFMA; P feeds straight from regs
  #pragma unroll
  for (int dt = 0; dt < 4; ++dt) {
    #pragma unroll
    for (int t = 0; t < 4; ++t) {
      half4v vf = *(const half4v*)(vsb + BUF * 8192 + dt * 2048 + vb[t]);
      #pragma unroll
      for (int qt = 0; qt < 2; ++qt)
        o[dt][qt] = __builtin_amdgcn_mfma_f32_16x16x16f16(vf, pf[t][qt], o[dt][qt], 0, 0, 0);
    }
  }
  __syncthreads();
}

__global__ __launch_bounds__(256, 3) void attn_kernel(
    const _Float16* __restrict__ Qm,   // [48][2048][64] (log2e-scaled)
    const _Float16* __restrict__ Km,   // [48][2048][64]
    const _Float16* __restrict__ Vt,   // [48][64][2048]
    float* __restrict__ out)           // [4][2048][768]
{
  __shared__ __attribute__((aligned(16))) _Float16 Ks[2 * 4096];
  __shared__ __attribute__((aligned(16))) _Float16 Vs[2 * 4096];
  const int bh = blockIdx.y;
  const int q0 = blockIdx.x * 128;
  const int tid = threadIdx.x, lane = tid & 63, w = tid >> 6;
  const int qd = lane >> 4, col = lane & 15, c7 = col & 7;
  const _Float16* Qg = Qm + (size_t)bh * 131072;
  const _Float16* Kg = Km + (size_t)bh * 131072;
  const _Float16* Vg = Vt + (size_t)bh * 131072;

  // Q fragments direct from global (kept in regs for the whole kernel)
  half8 qf[2][2];
  #pragma unroll
  for (int qt = 0; qt < 2; ++qt)
    #pragma unroll
    for (int ks = 0; ks < 2; ++ks)
      qf[qt][ks] = *(const half8*)(Qg + (size_t)(q0 + w * 32 + qt * 16 + col) * 64
                                   + (ks * 4 + qd) * 8);

  // loop-invariant per-lane LDS byte offsets (tile offsets fold into ds_read immediates)
  const int kb0 = col * 128 + ((qd ^ c7) * 16);
  const int kb1 = col * 128 + (((4 + qd) ^ c7) * 16);
  const int vq = (qd >> 1) ^ c7;
  int vb[4];
  #pragma unroll
  for (int t = 0; t < 4; ++t)
    vb[t] = col * 128 + (qd & 1) * 8 + ((vq ^ (2 * t)) * 16);

  float m[2] = {-1e30f, -1e30f};
  float l[2] = {0.f, 0.f};
  const floatx4 z4 = {0.f, 0.f, 0.f, 0.f};
  floatx4 o[4][2];
  #pragma unroll
  for (int dt = 0; dt < 4; ++dt)
    #pragma unroll
    for (int qt = 0; qt < 2; ++qt) o[dt][qt] = z4;

  stage_kv(Kg, Vg, Ks, Vs, 0, tid);
  __syncthreads();

  for (int jj = 0; jj < 2048; jj += 128) {
    attn_body<0>(jj + 64,  Kg, Vg, Ks, Vs, tid, qf, kb0, kb1, vb, m, l, o);
    attn_body<1>(jj + 128, Kg, Vg, Ks, Vs, tid, qf, kb0, kb1, vb, m, l, o);
  }

  // epilogue: out^T C-layout -> lane holds 4 consecutive d for fixed q -> float4 stores
  const int b = bh / 12, h = bh % 12;
  #pragma unroll
  for (int qt = 0; qt < 2; ++qt) {
    float inv = 1.0f / l[qt];
    int qg = q0 + w * 32 + qt * 16 + col;
    float* obase = out + ((size_t)b * 2048 + qg) * 768 + h * 64;
    #pragma unroll
    for (int dt = 0; dt < 4; ++dt) {
      floatx4 v = o[dt][qt];
      v[0] *= inv; v[1] *= inv; v[2] *= inv; v[3] *= inv;
      *(floatx4*)(obase + dt * 16 + qd * 4) = v;
    }
  }
}

// ---------------- launcher ----------------
extern "C" void kernel_launch(void* const* d_in, const int* in_sizes, int n_in,
                              void* d_out, int out_size, void* d_ws, size_t ws_size,
                              hipStream_t stream) {
  const float* q  = (const float*)d_in[0];
  const float* k  = (const float*)d_in[1];
  const float* v  = (const float*)d_in[2];
  const float* Wq = (const float*)d_in[3];
  const float* bq = (const float*)d_in[4];
  const float* Wk = (const float*)d_in[5];
  const float* bk = (const float*)d_in[6];
  const float* Wv = (const float*)d_in[7];
  const float* bv = (const float*)d_in[8];

  const size_t NX = 6291456;   // 4*2048*768
  const size_t NW = 589824;    // 768*768
  const size_t need = (3 * NX + 3 * NW + 3 * NX) * sizeof(_Float16);
  if (ws_size < need) return;

  _Float16* xh = (_Float16*)d_ws;            // [3][8192][768] f16 inputs
  _Float16* wh = xh + 3 * NX;                // [3][768][768] f16 weights
  _Float16* qh = wh + 3 * NW;                // Q' [48][2048][64] (log2e-scaled)
  _Float16* kh = qh + NX;                    // K' [48][2048][64]
  _Float16* vt = kh + NX;                    // V'^T [48][64][2048]

  CvtArgs ca;
  ca.src[0] = q;  ca.src[1] = k;  ca.src[2] = v;
  ca.src[3] = Wq; ca.src[4] = Wk; ca.src[5] = Wv;
  ca.dst[0] = xh;          ca.dst[1] = xh + NX;     ca.dst[2] = xh + 2 * NX;
  ca.dst[3] = wh;          ca.dst[4] = wh + NW;     ca.dst[5] = wh + 2 * NW;
  ca.n[0] = (int)NX; ca.n[1] = (int)NX; ca.n[2] = (int)NX;
  ca.n[3] = (int)NW; ca.n[4] = (int)NW; ca.n[5] = (int)NW;

  cvt_kernel<<<dim3(3072, 6), 256, 0, stream>>>(ca);
  qkv_gemm<<<dim3(64, 6, 3), 256, 0, stream>>>(xh, wh, bq, bk, bv, qh, kh, vt);
  attn_kernel<<<dim3(16, 48), 256, 0, stream>>>(qh, kh, vt, (float*)d_out);
}